// Round 10
// baseline (248.769 us; speedup 1.0000x reference)
//
#include <hip/hip_runtime.h>
#include <hip/hip_bf16.h>

#define NN 100000      // nodes
#define EE 1600000     // edges
#define CIN 128        // in channels
#define HID 64         // hidden
#define NG 64          // graphs
#define NOUT 10        // out channels
#define NBC2 782       // coarse buckets (128 targets each)
#define CCAP2 2432     // coarse capacity (mean 2048, +8.5 sigma)
#define NPB 6250       // pull blocks (16 targets each)
#define ZTOT (NBC2 + NG * HID + NG)  // ints zeroed in k_prep

typedef short s16x8 __attribute__((ext_vector_type(8)));
typedef float f32x4 __attribute__((ext_vector_type(4)));

__device__ __forceinline__ unsigned short f2b(float f) {  // f32 -> bf16 RNE
  unsigned int b = __float_as_uint(f);
  return (unsigned short)((b + 0x7FFFu + ((b >> 16) & 1u)) >> 16);
}
__device__ __forceinline__ float b2f_lo(unsigned int u) {
  return __uint_as_float(u << 16);
}
__device__ __forceinline__ float b2f_hi(unsigned int u) {
  return __uint_as_float(u & 0xFFFF0000u);
}

// ---------------------------------------------------------------------------
// K0: W prep (Wt[n][k] = bf16(W[k][n])) + zero the atomic counters/pool.
// ---------------------------------------------------------------------------
__global__ __launch_bounds__(256) void k_prep(const float* __restrict__ Wl,
                                              const float* __restrict__ Wr,
                                              unsigned short* __restrict__ Wt,
                                              int* __restrict__ zbuf) {
  int flat = blockIdx.x * 2048 + threadIdx.x;
#pragma unroll
  for (int i = 0; i < 8; ++i, flat += 256) {
    int n = flat & 127, k = flat >> 7;
    float v = (n < 64) ? Wl[k * 64 + n] : Wr[k * 64 + (n - 64)];
    Wt[n * 128 + k] = f2b(v);
  }
  for (int z = blockIdx.x * 256 + threadIdx.x; z < ZTOT; z += 2048)
    zbuf[z] = 0;
}

// ---------------------------------------------------------------------------
// K1: [xl|xr] = bf16( x @ [Wl|Wr] ) via mfma_f32_16x16x32_bf16.
// 64-row x 128-col tile, 4 waves (16 rows each), XOR-swizzled LDS.
// (structure validated rounds 6-8: absmax 4.9e-4)
// ---------------------------------------------------------------------------
__global__ __launch_bounds__(256) void k_gemm(
    const float* __restrict__ x, const unsigned short* __restrict__ Wt,
    unsigned short* __restrict__ xl, unsigned short* __restrict__ xr) {
  __shared__ unsigned short A[64 * 128];   // 16KB (reused as C buffer)
  __shared__ unsigned short B[128 * 128];  // 32KB
  const int tid = threadIdx.x;
  const int lane = tid & 63;
  const int w = tid >> 6;
  const int nb = blockIdx.x * 64;

  {  // stage B: 2048 16B units, swizzled
    int u = tid;
#pragma unroll
    for (int i = 0; i < 8; ++i, u += 256) {
      int n = u >> 4, slot = u & 15;
      uint4 v = *(const uint4*)((const char*)Wt + u * 16);
      int addr = n * 256 + ((slot * 16) ^ ((n & 7) << 4));
      *(uint4*)((char*)B + addr) = v;
    }
  }
  {  // stage A: 64 rows x 32 float4, convert to bf16, swizzled
    int f = tid;
#pragma unroll
    for (int i = 0; i < 8; ++i, f += 256) {
      int row = f >> 5, c4 = f & 31;
      int node = nb + row;
      float4 v = make_float4(0.f, 0.f, 0.f, 0.f);
      if (node < NN) v = *(const float4*)(x + (long)node * CIN + c4 * 4);
      uint2 p;
      p.x = (unsigned)f2b(v.x) | ((unsigned)f2b(v.y) << 16);
      p.y = (unsigned)f2b(v.z) | ((unsigned)f2b(v.w) << 16);
      int base16 = row * 256 + (((c4 >> 1) << 4) ^ ((row & 7) << 4));
      *(uint2*)((char*)A + base16 + (c4 & 1) * 8) = p;
    }
  }
  __syncthreads();

  const int m0 = w * 16;
  f32x4 acc[8];
#pragma unroll
  for (int nt = 0; nt < 8; ++nt) acc[nt] = (f32x4){0.f, 0.f, 0.f, 0.f};

#pragma unroll
  for (int ks = 0; ks < 4; ++ks) {
    const int kb2 = (ks * 32 + (lane >> 4) * 8) * 2;
    const int r0 = m0 + (lane & 15);
    s16x8 a0 = *(const s16x8*)((char*)A + r0 * 256 + (kb2 ^ ((r0 & 7) << 4)));
#pragma unroll
    for (int nt = 0; nt < 8; ++nt) {
      const int col = nt * 16 + (lane & 15);
      s16x8 b =
          *(const s16x8*)((char*)B + col * 256 + (kb2 ^ ((col & 7) << 4)));
      acc[nt] =
          __builtin_amdgcn_mfma_f32_16x16x32_bf16(a0, b, acc[nt], 0, 0, 0);
    }
  }
  __syncthreads();  // done reading A; reuse as C

  {
    const int rowb = m0 + (lane >> 4) * 4;
#pragma unroll
    for (int nt = 0; nt < 8; ++nt) {
      const int col = nt * 16 + (lane & 15);
#pragma unroll
      for (int r = 0; r < 4; ++r)
        *((unsigned short*)A + (rowb + r) * 128 + col) = f2b(acc[nt][r]);
    }
  }
  __syncthreads();

  {  // coalesced store: 1024 16B units; slot<8 -> xl, else xr
    int u = tid;
#pragma unroll
    for (int i = 0; i < 4; ++i, u += 256) {
      int row = u >> 4, slot = u & 15;
      int node = nb + row;
      if (node < NN) {
        uint4 v = *(const uint4*)((const char*)A + row * 256 + slot * 16);
        if (slot < 8)
          *(uint4*)((char*)xl + (long)node * 128 + slot * 16) = v;
        else
          *(uint4*)((char*)xr + (long)node * 128 + (slot - 8) * 16) = v;
      }
    }
  }
}

// ---------------------------------------------------------------------------
// Partition level 1: 782 coarse buckets (128 targets). Single global read
// (register-staged), LDS histogram + bulk reservation. Payload (s<<7)|(t&127).
// ---------------------------------------------------------------------------
__global__ __launch_bounds__(256) void k_coarse(const int* __restrict__ ei,
                                                int* __restrict__ gcurc,
                                                unsigned int* __restrict__ coarse) {
  __shared__ int hist[NBC2], lbase[NBC2], cur[NBC2];
  const int tid = threadIdx.x;
  const int base = blockIdx.x * 4096;
  int ss[16], tt[16];
  for (int b = tid; b < NBC2; b += 256) hist[b] = 0;
#pragma unroll
  for (int i = 0; i < 16; ++i) {
    int j = base + i * 256 + tid;
    if (j < EE) {
      ss[i] = ei[j];
      tt[i] = ei[EE + j];
    } else {
      tt[i] = -1;
    }
  }
  __syncthreads();
#pragma unroll
  for (int i = 0; i < 16; ++i)
    if (tt[i] >= 0) atomicAdd(&hist[tt[i] >> 7], 1);
  __syncthreads();
  for (int b = tid; b < NBC2; b += 256) {
    int c = hist[b];
    lbase[b] = c ? atomicAdd(gcurc + b, c) : 0;
    cur[b] = 0;
  }
  __syncthreads();
#pragma unroll
  for (int i = 0; i < 16; ++i) {
    if (tt[i] >= 0) {
      int cb = tt[i] >> 7;
      int p = lbase[cb] + atomicAdd(&cur[cb], 1);
      if (p < CCAP2)
        coarse[(long)cb * CCAP2 + p] =
            ((unsigned)ss[i] << 7) | (unsigned)(tt[i] & 127);
    }
  }
}

// ---------------------------------------------------------------------------
// Partition level 2: one block per coarse bucket (782 blocks) = sole writer.
// 128-way LDS counting sort; emits sorted src ids + per-target offsets.
// ---------------------------------------------------------------------------
__global__ __launch_bounds__(256) void k_fine(
    const int* __restrict__ gcurc, const unsigned int* __restrict__ coarse,
    unsigned int* __restrict__ buckets, unsigned short* __restrict__ sc16,
    int* __restrict__ gcnt) {
  __shared__ unsigned int staged[CCAP2];  // 9.5KB
  __shared__ int hist[128], sc[128], cur[128];
  const int tid = threadIdx.x;
  const int cb = blockIdx.x;
  const int ecnt = min(gcurc[cb], CCAP2);

  if (tid < 128) hist[tid] = 0;
  __syncthreads();
  for (int i = tid; i < ecnt; i += 256) {
    unsigned v = coarse[(long)cb * CCAP2 + i];
    staged[i] = v;
    atomicAdd(&hist[v & 127u], 1);
  }
  __syncthreads();

  // inclusive scan over 128 (waves 0,1 scan 64 each, then offset)
  if (tid < 128) {
    const int lane = tid & 63;
    int v = hist[tid], sum = v;
#pragma unroll
    for (int off = 1; off < 64; off <<= 1) {
      int t = __shfl_up(sum, off, 64);
      if (lane >= off) sum += t;
    }
    sc[tid] = sum;
  }
  __syncthreads();
  if (tid >= 64 && tid < 128) sc[tid] += sc[63];
  __syncthreads();
  if (tid < 128) {
    int st = sc[tid] - hist[tid];
    cur[tid] = st;
    sc16[(long)cb * 128 + tid] = (unsigned short)st;
  }
  if (tid == 0) gcnt[cb] = ecnt;
  __syncthreads();
  for (int i = tid; i < ecnt; i += 256) {
    unsigned v = staged[i];
    int p = atomicAdd(&cur[v & 127u], 1);
    buckets[(long)cb * CCAP2 + p] = v >> 7;  // plain src id
  }
}

// ---------------------------------------------------------------------------
// Pull: 128-thread blocks, 16 targets each (6250 blocks -> 24 blocks/CU
// oversubscription for load balance). 8 lanes x 8 ch per target, uint4
// gathers, x2 edge unroll, split-partial dot to shorten the FMA chain.
// No max-subtract (|e| small; identical after normalization).
// ---------------------------------------------------------------------------
__global__ __launch_bounds__(128) void k_pull2(
    const int* __restrict__ gcnt, const unsigned int* __restrict__ buckets,
    const unsigned short* __restrict__ sc16,
    const unsigned short* __restrict__ xl,
    const unsigned short* __restrict__ xr, const float* __restrict__ att,
    const float* __restrict__ bias, const int* __restrict__ batch,
    float* __restrict__ pooled, float* __restrict__ cnt) {
  __shared__ float pool2[2][HID];
  __shared__ float cnt2[2];
  const int tid = threadIdx.x;
  const int n0 = blockIdx.x * 16;
  pool2[tid >> 6][tid & 63] = 0.f;
  if (tid < 2) cnt2[tid] = 0.f;
  __syncthreads();

  const int l8 = tid & 7;  // channel octet
  const int d = tid >> 3;  // target within block (0..15)
  const int n = n0 + d;
  const int cb = n >> 7;
  const int tl = n & 127;
  float av[8];
  {
    float4 alo = *(const float4*)(att + l8 * 8);
    float4 ahi = *(const float4*)(att + l8 * 8 + 4);
    av[0] = alo.x; av[1] = alo.y; av[2] = alo.z; av[3] = alo.w;
    av[4] = ahi.x; av[5] = ahi.y; av[6] = ahi.z; av[7] = ahi.w;
  }
  float xt[8];
  {
    uint4 ur = *(const uint4*)(xr + (long)n * HID + l8 * 8);
    xt[0] = b2f_lo(ur.x); xt[1] = b2f_hi(ur.x);
    xt[2] = b2f_lo(ur.y); xt[3] = b2f_hi(ur.y);
    xt[4] = b2f_lo(ur.z); xt[5] = b2f_hi(ur.z);
    xt[6] = b2f_lo(ur.w); xt[7] = b2f_hi(ur.w);
  }
  float acc[8] = {0.f, 0.f, 0.f, 0.f, 0.f, 0.f, 0.f, 0.f};
  float den = 0.f;
  const int e0 = sc16[(long)cb * 128 + tl];
  const int e1 = (tl < 127) ? (int)sc16[(long)cb * 128 + tl + 1] : gcnt[cb];
  const unsigned int* brow = buckets + (long)cb * CCAP2;
  int e = e0;
  for (; e + 1 < e1; e += 2) {
    const int s0 = brow[e];
    const int s1 = brow[e + 1];
    const uint4 u0 = *(const uint4*)(xl + (long)s0 * HID + l8 * 8);
    const uint4 u1 = *(const uint4*)(xl + (long)s1 * HID + l8 * 8);
    float x0[8], x1[8];
    x0[0] = b2f_lo(u0.x); x0[1] = b2f_hi(u0.x);
    x0[2] = b2f_lo(u0.y); x0[3] = b2f_hi(u0.y);
    x0[4] = b2f_lo(u0.z); x0[5] = b2f_hi(u0.z);
    x0[6] = b2f_lo(u0.w); x0[7] = b2f_hi(u0.w);
    x1[0] = b2f_lo(u1.x); x1[1] = b2f_hi(u1.x);
    x1[2] = b2f_lo(u1.y); x1[3] = b2f_hi(u1.y);
    x1[4] = b2f_lo(u1.z); x1[5] = b2f_hi(u1.z);
    x1[6] = b2f_lo(u1.w); x1[7] = b2f_hi(u1.w);
    float p0a = 0.f, p0b = 0.f, p1a = 0.f, p1b = 0.f;
#pragma unroll
    for (int c = 0; c < 8; c += 2) {
      float za = x0[c] + xt[c];
      float zb = x0[c + 1] + xt[c + 1];
      za = za > 0.f ? za : 0.2f * za;
      zb = zb > 0.f ? zb : 0.2f * zb;
      p0a = fmaf(za, av[c], p0a);
      p0b = fmaf(zb, av[c + 1], p0b);
      float wa = x1[c] + xt[c];
      float wb = x1[c + 1] + xt[c + 1];
      wa = wa > 0.f ? wa : 0.2f * wa;
      wb = wb > 0.f ? wb : 0.2f * wb;
      p1a = fmaf(wa, av[c], p1a);
      p1b = fmaf(wb, av[c + 1], p1b);
    }
    float p0 = p0a + p0b;
    float p1 = p1a + p1b;
    p0 += __shfl_xor(p0, 1, 8);
    p1 += __shfl_xor(p1, 1, 8);
    p0 += __shfl_xor(p0, 2, 8);
    p1 += __shfl_xor(p1, 2, 8);
    p0 += __shfl_xor(p0, 4, 8);
    p1 += __shfl_xor(p1, 4, 8);
    const float a0 = __expf(p0);
    const float a1 = __expf(p1);
    den += a0 + a1;
#pragma unroll
    for (int c = 0; c < 8; ++c) {
      acc[c] = fmaf(a0, x0[c], acc[c]);
      acc[c] = fmaf(a1, x1[c], acc[c]);
    }
  }
  if (e < e1) {  // tail
    const int s0 = brow[e];
    const uint4 u0 = *(const uint4*)(xl + (long)s0 * HID + l8 * 8);
    float x0[8];
    x0[0] = b2f_lo(u0.x); x0[1] = b2f_hi(u0.x);
    x0[2] = b2f_lo(u0.y); x0[3] = b2f_hi(u0.y);
    x0[4] = b2f_lo(u0.z); x0[5] = b2f_hi(u0.z);
    x0[6] = b2f_lo(u0.w); x0[7] = b2f_hi(u0.w);
    float pa = 0.f, pb = 0.f;
#pragma unroll
    for (int c = 0; c < 8; c += 2) {
      float za = x0[c] + xt[c];
      float zb = x0[c + 1] + xt[c + 1];
      za = za > 0.f ? za : 0.2f * za;
      zb = zb > 0.f ? zb : 0.2f * zb;
      pa = fmaf(za, av[c], pa);
      pb = fmaf(zb, av[c + 1], pb);
    }
    float p0 = pa + pb;
    p0 += __shfl_xor(p0, 1, 8);
    p0 += __shfl_xor(p0, 2, 8);
    p0 += __shfl_xor(p0, 4, 8);
    const float a0 = __expf(p0);
    den += a0;
#pragma unroll
    for (int c = 0; c < 8; ++c) acc[c] = fmaf(a0, x0[c], acc[c]);
  }
  const float inv = 1.f / (den + 1e-16f);
  const int gr = batch[n];
  const int g0 = batch[n0];
  const int idx = gr - g0;
  float bv[8];
  {
    float4 blo = *(const float4*)(bias + l8 * 8);
    float4 bhi = *(const float4*)(bias + l8 * 8 + 4);
    bv[0] = blo.x; bv[1] = blo.y; bv[2] = blo.z; bv[3] = blo.w;
    bv[4] = bhi.x; bv[5] = bhi.y; bv[6] = bhi.z; bv[7] = bhi.w;
  }
  if (idx >= 0 && idx < 2) {
#pragma unroll
    for (int c = 0; c < 8; ++c)
      atomicAdd(&pool2[idx][l8 * 8 + c], fmaf(acc[c], inv, bv[c]));
    if (l8 == 0) atomicAdd(&cnt2[idx], 1.f);
  } else {  // safety net
#pragma unroll
    for (int c = 0; c < 8; ++c)
      atomicAdd(pooled + gr * HID + l8 * 8 + c, fmaf(acc[c], inv, bv[c]));
    if (l8 == 0) atomicAdd(cnt + gr, 1.f);
  }
  __syncthreads();
  {
    const int which = tid >> 6, c = tid & 63;
    const int gg = g0 + which;
    const float val = pool2[which][c];
    if (gg < NG && val != 0.f) atomicAdd(pooled + gg * HID + c, val);
  }
  if (tid < 2) {
    const int gg = g0 + tid;
    if (gg < NG && cnt2[tid] != 0.f) atomicAdd(cnt + gg, cnt2[tid]);
  }
}

// ---------------------------------------------------------------------------
// K4: pooled mean -> leaky(0.01) -> @fc_w + fc_b
// ---------------------------------------------------------------------------
__global__ void k_final(const float* __restrict__ pooled,
                        const float* __restrict__ cnt,
                        const float* __restrict__ fc_w,
                        const float* __restrict__ fc_b,
                        float* __restrict__ out) {
  const int tid = threadIdx.x;
  if (tid >= NG * NOUT) return;
  const int gr = tid / NOUT, o = tid % NOUT;
  const float cg = fmaxf(cnt[gr], 1.0f);
  float acc = fc_b[o];
#pragma unroll 8
  for (int h = 0; h < HID; ++h) {
    float pv = pooled[gr * HID + h] / cg;
    float hv = pv > 0.f ? pv : 0.01f * pv;
    acc = fmaf(hv, fc_w[h * NOUT + o], acc);
  }
  out[gr * NOUT + o] = acc;
}

extern "C" void kernel_launch(void* const* d_in, const int* in_sizes, int n_in,
                              void* d_out, int out_size, void* d_ws,
                              size_t ws_size, hipStream_t stream) {
  const float* x = (const float*)d_in[0];
  const float* Wl = (const float*)d_in[1];
  const float* Wr = (const float*)d_in[2];
  const float* att = (const float*)d_in[3];
  const float* bias = (const float*)d_in[4];
  const float* fc_w = (const float*)d_in[5];
  const float* fc_b = (const float*)d_in[6];
  const int* ei = (const int*)d_in[7];
  const int* batch = (const int*)d_in[8];
  float* out = (float*)d_out;

  char* w = (char*)d_ws;
  unsigned short* xl = (unsigned short*)w;      w += (long)NN * HID * 2;
  unsigned short* xr = (unsigned short*)w;      w += (long)NN * HID * 2;
  unsigned short* Wt = (unsigned short*)w;      w += 128 * 128 * 2;
  unsigned int* coarse = (unsigned int*)w;      w += (long)NBC2 * CCAP2 * 4;
  unsigned int* buckets = (unsigned int*)w;     w += (long)NBC2 * CCAP2 * 4;
  unsigned short* sc16 = (unsigned short*)w;    w += (long)NBC2 * 128 * 2;
  int* gcnt = (int*)w;                          w += NBC2 * 4;
  // zero span: gcurc .. pooled .. cnt (contiguous, ZTOT ints, by k_prep)
  int* gcurc = (int*)w;                         w += NBC2 * 4;
  float* pooled = (float*)w;                    w += NG * HID * 4;
  float* cnt = (float*)w;                       w += NG * 4;

  k_prep<<<8, 256, 0, stream>>>(Wl, Wr, Wt, gcurc);
  k_gemm<<<(NN + 63) / 64, 256, 0, stream>>>(x, Wt, xl, xr);
  k_coarse<<<(EE + 4095) / 4096, 256, 0, stream>>>(ei, gcurc, coarse);
  k_fine<<<NBC2, 256, 0, stream>>>(gcurc, coarse, buckets, sc16, gcnt);
  k_pull2<<<NPB, 128, 0, stream>>>(gcnt, buckets, sc16, xl, xr, att, bias,
                                   batch, pooled, cnt);
  k_final<<<1, NG * NOUT, 0, stream>>>(pooled, cnt, fc_w, fc_b, out);
}